// Round 1
// baseline (308.431 us; speedup 1.0000x reference)
//
#include <hip/hip_runtime.h>
#include <stdint.h>

// Decode fp16 bits -> f32 (exact, matches npy_halfbits_to_floatbits semantics).
__device__ __forceinline__ float h2f(uint32_t h) {
    uint32_t s = (h & 0x8000u) << 16;
    uint32_t e = (h >> 10) & 0x1fu;
    uint32_t m = h & 0x3ffu;
    if (e == 0) {
        // subnormal / zero: value = m * 2^-24 (exact in f32)
        float v = (float)m * 5.9604644775390625e-08f;  // 2^-24
        return __uint_as_float(s | __float_as_uint(v));
    }
    uint32_t fb;
    if (e == 31) fb = s | 0x7f800000u | (m << 13);      // inf / NaN (payload kept)
    else         fb = s | ((e + 112u) << 23) | (m << 13);
    return __uint_as_float(fb);
}

// f32 bits -> fp16 bits, RNE: verbatim port of numpy npy_floatbits_to_halfbits.
__device__ __forceinline__ uint32_t f2h(uint32_t f) {
    uint32_t h_sgn = (f & 0x80000000u) >> 16;
    uint32_t f_exp = f & 0x7f800000u;
    uint32_t f_sig;

    if (f_exp >= 0x47800000u) {
        if (f_exp == 0x7f800000u) {
            f_sig = f & 0x007fffffu;
            if (f_sig != 0u) {                 // NaN (not reached: handled by caller)
                uint32_t ret = 0x7c00u + (f_sig >> 13);
                if (ret == 0x7c00u) ret++;
                return h_sgn + ret;
            }
            return h_sgn + 0x7c00u;            // signed inf
        }
        return h_sgn + 0x7c00u;                // overflow -> signed inf
    }

    if (f_exp <= 0x38000000u) {                // subnormal half or zero
        if (f_exp < 0x33000000u) return h_sgn; // underflow -> signed zero
        uint32_t fe = f_exp >> 23;
        f_sig = 0x00800000u + (f & 0x007fffffu);
        f_sig >>= (113u - fe);
        // RNE; the shift can lose up to 11 bits, the || checks them in the original
        if (((f_sig & 0x00003fffu) != 0x00001000u) || (f & 0x000007ffu)) {
            f_sig += 0x00001000u;
        }
        return h_sgn + (f_sig >> 13);
    }

    // Regular case
    uint32_t h_exp = (f_exp - 0x38000000u) >> 13;
    f_sig = f & 0x007fffffu;
    if ((f_sig & 0x00003fffu) != 0x00001000u) {
        f_sig += 0x00001000u;                  // RNE
    }
    uint32_t h_sig = f_sig >> 13;
    // rounding spill into h_exp (possibly to inf) is correct via addition
    return h_sgn + h_exp + h_sig;
}

// Pack 4 spike floats (as raw u32 bit patterns; 1.0f has bit 23 set) into bits
// [top .. top-3] of u.
__device__ __forceinline__ uint32_t pack4(uint4 c, uint32_t u, int top) {
    u |= ((c.x >> 23) & 1u) << top;
    u |= ((c.y >> 23) & 1u) << (top - 1);
    u |= ((c.z >> 23) & 1u) << (top - 2);
    u |= ((c.w >> 23) & 1u) << (top - 3);
    return u;
}

__device__ __forceinline__ uint4 unpack4(uint32_t r, int top) {
    uint4 o;
    o.x = ((r >> top)       & 1u) * 0x3f800000u;
    o.y = ((r >> (top - 1)) & 1u) * 0x3f800000u;
    o.z = ((r >> (top - 2)) & 1u) * 0x3f800000u;
    o.w = ((r >> (top - 3)) & 1u) * 0x3f800000u;
    return o;
}

__global__ __launch_bounds__(256) void spike_fp16_add_kernel(
    const uint4* __restrict__ A, const uint4* __restrict__ B,
    uint4* __restrict__ O, int rows)
{
    int i = blockIdx.x * blockDim.x + threadIdx.x;
    if (i >= rows) return;

    const uint4* ap = A + (size_t)i * 4;
    const uint4* bp = B + (size_t)i * 4;

    uint4 a0 = ap[0], a1 = ap[1], a2 = ap[2], a3 = ap[3];
    uint4 b0 = bp[0], b1 = bp[1], b2 = bp[2], b3 = bp[3];

    uint32_t ua = 0, ub = 0;
    ua = pack4(a0, ua, 15); ua = pack4(a1, ua, 11);
    ua = pack4(a2, ua, 7);  ua = pack4(a3, ua, 3);
    ub = pack4(b0, ub, 15); ub = pack4(b1, ub, 11);
    ub = pack4(b2, ub, 7);  ub = pack4(b3, ub, 3);

    uint32_t ea = ua & 0x7fffu;
    uint32_t eb = ub & 0x7fffu;

    float fa = h2f(ua);
    float fb = h2f(ub);
    uint32_t r = f2h(__float_as_uint(fa + fb));

    // x86 addss semantics, matching the numpy reference:
    // inf + (-inf) -> indefinite QNaN 0xFE00; NaN in src1 (A) wins, quieted.
    if (ea == 0x7c00u && (ua ^ ub) == 0x8000u) r = 0xfe00u;
    if (eb > 0x7c00u) r = ub | 0x0200u;
    if (ea > 0x7c00u) r = ua | 0x0200u;

    uint4* op = O + (size_t)i * 4;
    op[0] = unpack4(r, 15);
    op[1] = unpack4(r, 11);
    op[2] = unpack4(r, 7);
    op[3] = unpack4(r, 3);
}

extern "C" void kernel_launch(void* const* d_in, const int* in_sizes, int n_in,
                              void* d_out, int out_size, void* d_ws, size_t ws_size,
                              hipStream_t stream) {
    const uint4* A = (const uint4*)d_in[0];
    const uint4* B = (const uint4*)d_in[1];
    uint4* O = (uint4*)d_out;
    int rows = in_sizes[0] / 16;   // 2,097,152
    int threads = 256;
    int blocks = (rows + threads - 1) / threads;
    spike_fp16_add_kernel<<<blocks, threads, 0, stream>>>(A, B, O, rows);
}

// Round 2
// 305.483 us; speedup vs baseline: 1.0096x; 1.0096x over previous
//
#include <hip/hip_runtime.h>
#include <stdint.h>

// ---------- exact numpy-compatible fp16 add on raw bit patterns ----------

// fp16 bits -> f32 (exact, matches npy_halfbits_to_floatbits).
__device__ __forceinline__ float h2f(uint32_t h) {
    uint32_t s = (h & 0x8000u) << 16;
    uint32_t e = (h >> 10) & 0x1fu;
    uint32_t m = h & 0x3ffu;
    if (e == 0) {
        float v = (float)m * 5.9604644775390625e-08f;  // m * 2^-24, exact
        return __uint_as_float(s | __float_as_uint(v));
    }
    uint32_t fb;
    if (e == 31) fb = s | 0x7f800000u | (m << 13);
    else         fb = s | ((e + 112u) << 23) | (m << 13);
    return __uint_as_float(fb);
}

// f32 bits -> fp16 bits, RNE: port of numpy npy_floatbits_to_halfbits.
__device__ __forceinline__ uint32_t f2h(uint32_t f) {
    uint32_t h_sgn = (f & 0x80000000u) >> 16;
    uint32_t f_exp = f & 0x7f800000u;
    uint32_t f_sig;

    if (f_exp >= 0x47800000u) {
        if (f_exp == 0x7f800000u) {
            f_sig = f & 0x007fffffu;
            if (f_sig != 0u) {
                uint32_t ret = 0x7c00u + (f_sig >> 13);
                if (ret == 0x7c00u) ret++;
                return h_sgn + ret;
            }
            return h_sgn + 0x7c00u;
        }
        return h_sgn + 0x7c00u;                // overflow -> signed inf
    }

    if (f_exp <= 0x38000000u) {                // subnormal half or zero
        if (f_exp < 0x33000000u) return h_sgn; // underflow -> signed zero
        uint32_t fe = f_exp >> 23;
        f_sig = 0x00800000u + (f & 0x007fffffu);
        f_sig >>= (113u - fe);
        if (((f_sig & 0x00003fffu) != 0x00001000u) || (f & 0x000007ffu)) {
            f_sig += 0x00001000u;              // RNE
        }
        return h_sgn + (f_sig >> 13);
    }

    uint32_t h_exp = (f_exp - 0x38000000u) >> 13;
    f_sig = f & 0x007fffffu;
    if ((f_sig & 0x00003fffu) != 0x00001000u) {
        f_sig += 0x00001000u;                  // RNE
    }
    uint32_t h_sig = f_sig >> 13;
    return h_sgn + h_exp + h_sig;              // rounding spill is correct via add
}

// Full fp16 add with x86-addss / numpy special-case semantics.
__device__ __forceinline__ uint32_t fp16_add(uint32_t ua, uint32_t ub) {
    uint32_t ea = ua & 0x7fffu;
    uint32_t eb = ub & 0x7fffu;
    uint32_t r = f2h(__float_as_uint(h2f(ua) + h2f(ub)));
    if (ea == 0x7c00u && (ua ^ ub) == 0x8000u) r = 0xfe00u;  // inf + (-inf)
    if (eb > 0x7c00u) r = ub | 0x0200u;                      // NaN quieting,
    if (ea > 0x7c00u) r = ua | 0x0200u;                      // src1 (A) wins
    return r;
}

// ---------- spike <-> nibble helpers ----------

// Pack 4 spike floats (raw u32; 1.0f has bit 23 set) into bits [top..top-3].
__device__ __forceinline__ uint32_t pack4(uint4 c, int top) {
    uint32_t u = 0;
    u |= ((c.x >> 23) & 1u) << top;
    u |= ((c.y >> 23) & 1u) << (top - 1);
    u |= ((c.z >> 23) & 1u) << (top - 2);
    u |= ((c.w >> 23) & 1u) << (top - 3);
    return u;
}

__device__ __forceinline__ uint4 unpack4(uint32_t r, int top) {
    uint4 o;
    o.x = ((r >> top)       & 1u) * 0x3f800000u;
    o.y = ((r >> (top - 1)) & 1u) * 0x3f800000u;
    o.z = ((r >> (top - 2)) & 1u) * 0x3f800000u;
    o.w = ((r >> (top - 3)) & 1u) * 0x3f800000u;
    return o;
}

// OR-reduce across aligned groups of 4 lanes (DPP-friendly shfl_xor).
__device__ __forceinline__ uint32_t orreduce4(uint32_t v) {
    v |= __shfl_xor(v, 1, 64);
    v |= __shfl_xor(v, 2, 64);
    return v;
}

// ---------- kernel ----------
// Block = 256 threads handles 256 rows (= 1024 uint4 per array), fully
// coalesced: thread t loads/stores flat uint4 indices base + t + 256*k.
// Thread t holds chunk c = t&3 (nibble at bits [15-4c .. 12-4c]) of rows
// (t>>2) + 64*k. 4-lane shfl_xor OR assembles full 16-bit words; each lane
// computes all 4 adds redundantly (VALU is ~9% busy — redundancy is free)
// and writes back only its own nibble.
__global__ __launch_bounds__(256) void spike_fp16_add_kernel(
    const uint4* __restrict__ A, const uint4* __restrict__ B,
    uint4* __restrict__ O)
{
    const int t = threadIdx.x;
    const int c = t & 3;
    const int top = 15 - 4 * c;                 // nibble position for chunk c
    const size_t base = (size_t)blockIdx.x * 1024;

    uint4 a0 = A[base + t];
    uint4 a1 = A[base + t + 256];
    uint4 a2 = A[base + t + 512];
    uint4 a3 = A[base + t + 768];
    uint4 b0 = B[base + t];
    uint4 b1 = B[base + t + 256];
    uint4 b2 = B[base + t + 512];
    uint4 b3 = B[base + t + 768];

    uint32_t ua0 = orreduce4(pack4(a0, top));
    uint32_t ua1 = orreduce4(pack4(a1, top));
    uint32_t ua2 = orreduce4(pack4(a2, top));
    uint32_t ua3 = orreduce4(pack4(a3, top));
    uint32_t ub0 = orreduce4(pack4(b0, top));
    uint32_t ub1 = orreduce4(pack4(b1, top));
    uint32_t ub2 = orreduce4(pack4(b2, top));
    uint32_t ub3 = orreduce4(pack4(b3, top));

    uint32_t r0 = fp16_add(ua0, ub0);
    uint32_t r1 = fp16_add(ua1, ub1);
    uint32_t r2 = fp16_add(ua2, ub2);
    uint32_t r3 = fp16_add(ua3, ub3);

    O[base + t]       = unpack4(r0, top);
    O[base + t + 256] = unpack4(r1, top);
    O[base + t + 512] = unpack4(r2, top);
    O[base + t + 768] = unpack4(r3, top);
}

extern "C" void kernel_launch(void* const* d_in, const int* in_sizes, int n_in,
                              void* d_out, int out_size, void* d_ws, size_t ws_size,
                              hipStream_t stream) {
    const uint4* A = (const uint4*)d_in[0];
    const uint4* B = (const uint4*)d_in[1];
    uint4* O = (uint4*)d_out;
    int rows = in_sizes[0] / 16;               // 2,097,152 (multiple of 256)
    int blocks = rows / 256;
    spike_fp16_add_kernel<<<blocks, 256, 0, stream>>>(A, B, O);
}

// Round 3
// 287.985 us; speedup vs baseline: 1.0710x; 1.0608x over previous
//
#include <hip/hip_runtime.h>
#include <stdint.h>

// True vector type so __builtin_nontemporal_{load,store} accepts it
// (HIP's uint4 is a struct; the builtin needs a scalar/vector type).
typedef uint32_t u32x4 __attribute__((ext_vector_type(4)));

// ---------- exact numpy-compatible fp16 add on raw bit patterns ----------

// fp16 bits -> f32 (exact, matches npy_halfbits_to_floatbits).
__device__ __forceinline__ float h2f(uint32_t h) {
    uint32_t s = (h & 0x8000u) << 16;
    uint32_t e = (h >> 10) & 0x1fu;
    uint32_t m = h & 0x3ffu;
    if (e == 0) {
        float v = (float)m * 5.9604644775390625e-08f;  // m * 2^-24, exact
        return __uint_as_float(s | __float_as_uint(v));
    }
    uint32_t fb;
    if (e == 31) fb = s | 0x7f800000u | (m << 13);
    else         fb = s | ((e + 112u) << 23) | (m << 13);
    return __uint_as_float(fb);
}

// f32 bits -> fp16 bits, RNE: port of numpy npy_floatbits_to_halfbits.
__device__ __forceinline__ uint32_t f2h(uint32_t f) {
    uint32_t h_sgn = (f & 0x80000000u) >> 16;
    uint32_t f_exp = f & 0x7f800000u;
    uint32_t f_sig;

    if (f_exp >= 0x47800000u) {
        if (f_exp == 0x7f800000u) {
            f_sig = f & 0x007fffffu;
            if (f_sig != 0u) {
                uint32_t ret = 0x7c00u + (f_sig >> 13);
                if (ret == 0x7c00u) ret++;
                return h_sgn + ret;
            }
            return h_sgn + 0x7c00u;
        }
        return h_sgn + 0x7c00u;                // overflow -> signed inf
    }

    if (f_exp <= 0x38000000u) {                // subnormal half or zero
        if (f_exp < 0x33000000u) return h_sgn; // underflow -> signed zero
        uint32_t fe = f_exp >> 23;
        f_sig = 0x00800000u + (f & 0x007fffffu);
        f_sig >>= (113u - fe);
        if (((f_sig & 0x00003fffu) != 0x00001000u) || (f & 0x000007ffu)) {
            f_sig += 0x00001000u;              // RNE
        }
        return h_sgn + (f_sig >> 13);
    }

    uint32_t h_exp = (f_exp - 0x38000000u) >> 13;
    f_sig = f & 0x007fffffu;
    if ((f_sig & 0x00003fffu) != 0x00001000u) {
        f_sig += 0x00001000u;                  // RNE
    }
    uint32_t h_sig = f_sig >> 13;
    return h_sgn + h_exp + h_sig;              // rounding spill is correct via add
}

// Full fp16 add with x86-addss / numpy special-case semantics.
__device__ __forceinline__ uint32_t fp16_add(uint32_t ua, uint32_t ub) {
    uint32_t ea = ua & 0x7fffu;
    uint32_t eb = ub & 0x7fffu;
    uint32_t r = f2h(__float_as_uint(h2f(ua) + h2f(ub)));
    if (ea == 0x7c00u && (ua ^ ub) == 0x8000u) r = 0xfe00u;  // inf + (-inf)
    if (eb > 0x7c00u) r = ub | 0x0200u;                      // NaN quieting,
    if (ea > 0x7c00u) r = ua | 0x0200u;                      // src1 (A) wins
    return r;
}

// ---------- spike <-> nibble helpers ----------

// Pack 4 spike floats (raw u32; 1.0f has bit 23 set) into bits [top..top-3].
__device__ __forceinline__ uint32_t pack4(u32x4 c, int top) {
    uint32_t u = 0;
    u |= ((c.x >> 23) & 1u) << top;
    u |= ((c.y >> 23) & 1u) << (top - 1);
    u |= ((c.z >> 23) & 1u) << (top - 2);
    u |= ((c.w >> 23) & 1u) << (top - 3);
    return u;
}

__device__ __forceinline__ u32x4 unpack4(uint32_t r, int top) {
    u32x4 o;
    o.x = ((r >> top)       & 1u) * 0x3f800000u;
    o.y = ((r >> (top - 1)) & 1u) * 0x3f800000u;
    o.z = ((r >> (top - 2)) & 1u) * 0x3f800000u;
    o.w = ((r >> (top - 3)) & 1u) * 0x3f800000u;
    return o;
}

// OR-reduce across aligned groups of 4 lanes (DPP-friendly shfl_xor).
__device__ __forceinline__ uint32_t orreduce4(uint32_t v) {
    v |= __shfl_xor(v, 1, 64);
    v |= __shfl_xor(v, 2, 64);
    return v;
}

// ---------- kernel ----------
// Identical structure to R2 (fully coalesced; thread t owns chunk c = t&3 of
// rows (t>>2)+64k; 4-lane shfl_xor OR assembles the 16-bit words), but ALL
// global accesses are non-temporal: A/B are read-once, O is write-once.
// Goal: stop our own allocations from evicting the L3-resident input half
// (the harness restore leaves ~half the inputs hot in the 256 MiB L3).
__global__ __launch_bounds__(256) void spike_fp16_add_kernel(
    const u32x4* __restrict__ A, const u32x4* __restrict__ B,
    u32x4* __restrict__ O)
{
    const int t = threadIdx.x;
    const int c = t & 3;
    const int top = 15 - 4 * c;                 // nibble position for chunk c
    const size_t base = (size_t)blockIdx.x * 1024;

    u32x4 a0 = __builtin_nontemporal_load(&A[base + t]);
    u32x4 a1 = __builtin_nontemporal_load(&A[base + t + 256]);
    u32x4 a2 = __builtin_nontemporal_load(&A[base + t + 512]);
    u32x4 a3 = __builtin_nontemporal_load(&A[base + t + 768]);
    u32x4 b0 = __builtin_nontemporal_load(&B[base + t]);
    u32x4 b1 = __builtin_nontemporal_load(&B[base + t + 256]);
    u32x4 b2 = __builtin_nontemporal_load(&B[base + t + 512]);
    u32x4 b3 = __builtin_nontemporal_load(&B[base + t + 768]);

    uint32_t ua0 = orreduce4(pack4(a0, top));
    uint32_t ua1 = orreduce4(pack4(a1, top));
    uint32_t ua2 = orreduce4(pack4(a2, top));
    uint32_t ua3 = orreduce4(pack4(a3, top));
    uint32_t ub0 = orreduce4(pack4(b0, top));
    uint32_t ub1 = orreduce4(pack4(b1, top));
    uint32_t ub2 = orreduce4(pack4(b2, top));
    uint32_t ub3 = orreduce4(pack4(b3, top));

    uint32_t r0 = fp16_add(ua0, ub0);
    uint32_t r1 = fp16_add(ua1, ub1);
    uint32_t r2 = fp16_add(ua2, ub2);
    uint32_t r3 = fp16_add(ua3, ub3);

    __builtin_nontemporal_store(unpack4(r0, top), &O[base + t]);
    __builtin_nontemporal_store(unpack4(r1, top), &O[base + t + 256]);
    __builtin_nontemporal_store(unpack4(r2, top), &O[base + t + 512]);
    __builtin_nontemporal_store(unpack4(r3, top), &O[base + t + 768]);
}

extern "C" void kernel_launch(void* const* d_in, const int* in_sizes, int n_in,
                              void* d_out, int out_size, void* d_ws, size_t ws_size,
                              hipStream_t stream) {
    const u32x4* A = (const u32x4*)d_in[0];
    const u32x4* B = (const u32x4*)d_in[1];
    u32x4* O = (u32x4*)d_out;
    int rows = in_sizes[0] / 16;               // 2,097,152 (multiple of 256)
    int blocks = rows / 256;
    spike_fp16_add_kernel<<<blocks, 256, 0, stream>>>(A, B, O);
}